// Round 1
// baseline (4913.234 us; speedup 1.0000x reference)
//
#include <hip/hip_runtime.h>
#include <cmath>
#include <complex>
#include <vector>
#include <algorithm>

#define DEVFN __device__ __forceinline__

namespace {

constexpr int TILE_Z = 8;
constexpr int NNODE  = 50000;
constexpr int NBLOCK = NNODE / TILE_Z;   // 6250, exact

// INSTR = [(0,0,0),(0,1,1),(0,2,2),(1,0,1),(1,1,0),(1,1,1),(1,1,2),(1,2,1),
//          (1,2,2),(2,0,2),(2,1,1),(2,1,2),(2,2,0),(2,2,1),(2,2,2)]
constexpr int I_L1[15] = {0,0,0,1,1,1,1,1,1,2,2,2,2,2,2};
constexpr int I_L2[15] = {0,1,2,0,1,1,1,2,2,0,1,1,2,2,2};
constexpr int I_LO[15] = {0,1,2,1,0,1,2,1,2,2,1,2,0,1,2};
// flattened w3j table offsets; sizes (2l1+1)(2l2+1)(2lo+1):
// 1,9,25,9,9,27,45,45,75,25,45,75,25,75,125 -> total 615
constexpr int W3OFF[15] = {0,1,10,35,44,53,80,125,170,245,270,315,390,415,490};
constexpr int LOFF[3] = {0,1,4};     // basis-dim offset of each l block

struct TPParams { float w3j[615]; float alpha[15]; };

// ---------------- host: e3nn-convention wigner 3j (mirrors reference) -------
double ffact(int n){ double r=1.0; for(int i=2;i<=n;++i) r*=i; return r; }

double su2cg(int j1,int m1,int j2,int m2,int j3,int m3){
  if(m3 != m1+m2) return 0.0;
  int vmin = std::max(std::max(-j1+j2+m3, -j1+m1), 0);
  int vmax = std::min(std::min(j2+j3+m1, j3-j1+j2), j3+m3);
  double C = std::sqrt((2.0*j3+1.0)*ffact(j3+j1-j2)*ffact(j3-j1+j2)*ffact(j1+j2-j3)
             /ffact(j1+j2+j3+1)
             *ffact(j3+m3)*ffact(j3-m3)
             /(ffact(j1-m1)*ffact(j1+m1)*ffact(j2-m2)*ffact(j2+m2)));
  double S = 0.0;
  for(int v=vmin; v<=vmax; ++v){
    double t = ffact(j2+j3+m1-v)*ffact(j1-m1+v)
             /(ffact(v)*ffact(j3-j1+j2-v)*ffact(j3+m3-v)*ffact(v+j1-j2-m3));
    S += ((v+j2+m2)&1) ? -t : t;
  }
  return C*S;
}

void cbasis(int l, std::complex<double>* q){
  int n = 2*l+1;
  for(int i=0;i<n*n;++i) q[i] = std::complex<double>(0.0,0.0);
  const double is2 = 1.0/std::sqrt(2.0);
  for(int m=-l; m<0; ++m){
    q[(l+m)*n + (l-m)] = std::complex<double>(is2, 0.0);   // col l+|m|
    q[(l+m)*n + (l+m)] = std::complex<double>(0.0, -is2);  // col l-|m|
  }
  q[l*n+l] = std::complex<double>(1.0, 0.0);
  for(int m=1; m<=l; ++m){
    double s = (m&1) ? -1.0 : 1.0;                         // (-1)^m
    q[(l+m)*n + (l+m)] = std::complex<double>(s*is2, 0.0);
    q[(l+m)*n + (l-m)] = std::complex<double>(0.0, s*is2);
  }
  std::complex<double> ph;
  switch(l&3){ case 0: ph = std::complex<double>(1,0);  break;
               case 1: ph = std::complex<double>(0,-1); break;
               case 2: ph = std::complex<double>(-1,0); break;
               default: ph = std::complex<double>(0,1);  break; }  // (-1j)^l
  for(int i=0;i<n*n;++i) q[i] *= ph;
}

void wigner3j_tab(int l1,int l2,int l3, float* dst){
  int n1=2*l1+1, n2=2*l2+1, n3=2*l3+1;
  std::vector<double> C(n1*n2*n3);
  for(int i=0;i<n1;++i) for(int k=0;k<n2;++k) for(int n=0;n<n3;++n)
    C[(i*n2+k)*n3+n] = su2cg(l1,i-l1, l2,k-l2, l3,n-l3);
  std::vector<std::complex<double>> Q1(n1*n1), Q2(n2*n2), Q3(n3*n3);
  cbasis(l1,Q1.data()); cbasis(l2,Q2.data()); cbasis(l3,Q3.data());
  std::vector<double> R(n1*n2*n3, 0.0);
  // out[j,l,m] = sum_{i,k,n} Q1[i,j] Q2[k,l] conj(Q3[n,m]) C[i,k,n]  (real part)
  for(int j=0;j<n1;++j) for(int l=0;l<n2;++l) for(int m=0;m<n3;++m){
    std::complex<double> s(0,0);
    for(int i=0;i<n1;++i) for(int k=0;k<n2;++k) for(int n=0;n<n3;++n)
      s += Q1[i*n1+j]*Q2[k*n2+l]*std::conj(Q3[n*n3+m])*C[(i*n2+k)*n3+n];
    R[(j*n2+l)*n3+m] = s.real();
  }
  double nrm=0; for(double v:R) nrm += v*v; nrm = std::sqrt(nrm);
  for(int t=0;t<n1*n2*n3;++t) dst[t] = (float)(R[t]/nrm);
}

void fill_params(TPParams& P){
  for(int ins=0; ins<15; ++ins)
    wigner3j_tab(I_L1[ins], I_L2[ins], I_LO[ins], P.w3j + W3OFF[ins]);
  int cnt[3] = {0,0,0};
  for(int ins=0; ins<15; ++ins) cnt[I_LO[ins]]++;      // {3,6,6}
  for(int ins=0; ins<15; ++ins){
    int lo = I_LO[ins];
    P.alpha[ins] = (float)std::sqrt((2.0*lo+1.0)/(128.0*cnt[lo]));
  }
}

} // namespace

// ---------------- device ----------------------------------------------------
DEVFN unsigned f2bf(float f){                       // fp32 -> bf16 bits (RNE)
  unsigned u = __float_as_uint(f);
  return (u + 0x7fffu + ((u>>16)&1u)) >> 16;
}
DEVFN float bf2f(unsigned b){ return __uint_as_float(b<<16); }

template<int INS>
DEVFN void do_instr(const TPParams& P, const float* __restrict__ weight,
                    float acc[4][9],
                    const unsigned short* sx1, float* sWT, float* sxx,
                    const float* sx2, int tid)
{
  constexpr int L1 = I_L1[INS], L2 = I_L2[INS], LO = I_LO[INS];
  constexpr int N1 = 2*L1+1, N2 = 2*L2+1, NO = 2*LO+1;
  constexpr int O1 = LOFF[L1], O2 = LOFF[L2], OO = LOFF[LO];
  constexpr int W3 = W3OFF[INS];

  const int z = tid >> 5;                 // 8 nodes, 32 threads each
  // ---- phase A: xx[z][k][u] = sum_i (alpha * sum_j w3j[i,j,k] x2[j]) * x1[i,u]
  {
    const int u0 = (tid & 31) * 4;
    float cc[NO][N1];
    #pragma unroll
    for(int k=0;k<NO;++k){
      #pragma unroll
      for(int i=0;i<N1;++i){
        float s = 0.f;
        #pragma unroll
        for(int j=0;j<N2;++j)
          s += P.w3j[W3 + (i*N2+j)*NO + k] * sx2[z*9 + O2 + j];
        cc[k][i] = s * P.alpha[INS];
      }
    }
    float xr[N1][4];
    #pragma unroll
    for(int i=0;i<N1;++i){
      uint2 u = *reinterpret_cast<const uint2*>(&sx1[(z*9 + O1 + i)*128 + u0]);
      xr[i][0]=bf2f(u.x & 0xffffu); xr[i][1]=bf2f(u.x>>16);
      xr[i][2]=bf2f(u.y & 0xffffu); xr[i][3]=bf2f(u.y>>16);
    }
    #pragma unroll
    for(int k=0;k<NO;++k){
      float r0=0.f,r1=0.f,r2=0.f,r3=0.f;
      #pragma unroll
      for(int i=0;i<N1;++i){
        r0 += cc[k][i]*xr[i][0]; r1 += cc[k][i]*xr[i][1];
        r2 += cc[k][i]*xr[i][2]; r3 += cc[k][i]*xr[i][3];
      }
      *reinterpret_cast<float4*>(&sxx[(z*5 + k)*128 + u0]) = make_float4(r0,r1,r2,r3);
    }
  }
  __syncthreads();

  // ---- phase B: acc[c][OO+k] += sum_u xx[z][k][u] * W[u][w],  w = wg+32c
  const int w    = tid & 127;
  const int half = tid >> 7;
  const int wg   = tid & 31;
  const int swz  = 4*((wg>>3)&3);      // XOR swizzle keeps b128 reads conflict-free
  const int wswz = 4*((w>>3)&3);
  #pragma unroll 1
  for(int q=0;q<4;++q){                // stage W in 32-u quarters (LDS budget)
    const float* wsrc = weight + INS*16384 + q*32*128;
    #pragma unroll
    for(int r=0;r<16;++r){
      int ui = half + r*2;
      sWT[w*36 + (ui ^ wswz)] = wsrc[ui*128 + w];   // transposed, padded stride 36
    }
    __syncthreads();
    #pragma unroll 1
    for(int u4=0;u4<8;++u4){
      const int uloc  = u4*4;
      const int uglob = q*32 + uloc;
      float4 xv[NO];
      #pragma unroll
      for(int k=0;k<NO;++k)
        xv[k] = *reinterpret_cast<const float4*>(&sxx[(z*5+k)*128 + uglob]);
      #pragma unroll
      for(int c4=0;c4<4;++c4){
        float4 wv = *reinterpret_cast<const float4*>(&sWT[(wg+32*c4)*36 + (uloc ^ swz)]);
        #pragma unroll
        for(int k=0;k<NO;++k)
          acc[c4][OO+k] += xv[k].x*wv.x + xv[k].y*wv.y + xv[k].z*wv.z + xv[k].w*wv.w;
      }
    }
    __syncthreads();
  }
}

__global__ __launch_bounds__(256, 2)
void tp_kernel(const float* __restrict__ x1, const float* __restrict__ x2,
               const float* __restrict__ weight, float* __restrict__ out,
               TPParams P)
{
  __shared__ unsigned short sx1[TILE_Z*9*128];  // bf16 bits, 18432 B
  __shared__ float sWT[128*36];                 // 18432 B
  __shared__ float sxx[TILE_Z*5*128];           // 20480 B
  __shared__ float sx2[TILE_Z*9];               // 288 B   (total 57.6 KB -> 2 blk/CU)

  const int tid = threadIdx.x;
  const long zbase = (long)blockIdx.x * TILE_Z;

  {
    const float4* src = reinterpret_cast<const float4*>(x1 + zbase*1152);
    uint2* dst = reinterpret_cast<uint2*>(sx1);
    #pragma unroll
    for(int r=0;r<9;++r){                       // 8*1152/4 = 2304 float4 / 256
      int it = tid + r*256;
      float4 v = src[it];
      dst[it] = make_uint2(f2bf(v.x) | (f2bf(v.y)<<16),
                           f2bf(v.z) | (f2bf(v.w)<<16));
    }
    if(tid < TILE_Z*9) sx2[tid] = x2[zbase*9 + tid];
  }
  __syncthreads();

  float acc[4][9];
  #pragma unroll
  for(int a=0;a<4;++a){
    #pragma unroll
    for(int b=0;b<9;++b) acc[a][b]=0.f;
  }

  do_instr< 0>(P,weight,acc,sx1,sWT,sxx,sx2,tid);
  do_instr< 1>(P,weight,acc,sx1,sWT,sxx,sx2,tid);
  do_instr< 2>(P,weight,acc,sx1,sWT,sxx,sx2,tid);
  do_instr< 3>(P,weight,acc,sx1,sWT,sxx,sx2,tid);
  do_instr< 4>(P,weight,acc,sx1,sWT,sxx,sx2,tid);
  do_instr< 5>(P,weight,acc,sx1,sWT,sxx,sx2,tid);
  do_instr< 6>(P,weight,acc,sx1,sWT,sxx,sx2,tid);
  do_instr< 7>(P,weight,acc,sx1,sWT,sxx,sx2,tid);
  do_instr< 8>(P,weight,acc,sx1,sWT,sxx,sx2,tid);
  do_instr< 9>(P,weight,acc,sx1,sWT,sxx,sx2,tid);
  do_instr<10>(P,weight,acc,sx1,sWT,sxx,sx2,tid);
  do_instr<11>(P,weight,acc,sx1,sWT,sxx,sx2,tid);
  do_instr<12>(P,weight,acc,sx1,sWT,sxx,sx2,tid);
  do_instr<13>(P,weight,acc,sx1,sWT,sxx,sx2,tid);
  do_instr<14>(P,weight,acc,sx1,sWT,sxx,sx2,tid);

  const int z = tid>>5, wg = tid&31;
  float* op = out + (zbase + z)*1152;
  #pragma unroll
  for(int c4=0;c4<4;++c4){
    #pragma unroll
    for(int t=0;t<9;++t)
      op[t*128 + wg + 32*c4] = acc[c4][t];
  }
}

extern "C" void kernel_launch(void* const* d_in, const int* in_sizes, int n_in,
                              void* d_out, int out_size, void* d_ws, size_t ws_size,
                              hipStream_t stream)
{
  (void)in_sizes; (void)n_in; (void)out_size; (void)d_ws; (void)ws_size;
  const float* x1 = (const float*)d_in[0];
  const float* x2 = (const float*)d_in[1];
  const float* wt = (const float*)d_in[2];
  float* out = (float*)d_out;

  TPParams P;                 // host-computed constants, baked into graph as kernarg
  fill_params(P);

  tp_kernel<<<dim3(NBLOCK), dim3(256), 0, stream>>>(x1, x2, wt, out, P);
}

// Round 2
// 501.674 us; speedup vs baseline: 9.7937x; 9.7937x over previous
//
#include <hip/hip_runtime.h>
#include <cmath>
#include <complex>
#include <vector>
#include <algorithm>

#define DEVFN __device__ __forceinline__

typedef short short8 __attribute__((ext_vector_type(8)));
typedef float f32x4  __attribute__((ext_vector_type(4)));

namespace {

constexpr int NNODE  = 50000;
constexpr int TILE_Z = 16;
constexpr int NBLOCK = NNODE / TILE_Z;   // 3125, exact
static_assert(NBLOCK * TILE_Z == NNODE, "tile");

// INSTR = [(0,0,0),(0,1,1),(0,2,2),(1,0,1),(1,1,0),(1,1,1),(1,1,2),(1,2,1),
//          (1,2,2),(2,0,2),(2,1,1),(2,1,2),(2,2,0),(2,2,1),(2,2,2)]
constexpr int I_L1[15] = {0,0,0,1,1,1,1,1,1,2,2,2,2,2,2};
constexpr int I_L2[15] = {0,1,2,0,1,1,1,2,2,0,1,1,2,2,2};
constexpr int I_LO[15] = {0,1,2,1,0,1,2,1,2,2,1,2,0,1,2};
// flattened w3j offsets; sizes (2l1+1)(2l2+1)(2lo+1) -> total 615
constexpr int W3OFF[15] = {0,1,10,35,44,53,80,125,170,245,270,315,390,415,490};
constexpr int LOFF[3] = {0,1,4};     // basis-dim offset of each l block

struct TPParams { float w3j[615]; };
struct AlphaArg { float a[15]; };

// ---------------- host: e3nn-convention wigner 3j (proven in R1) ------------
double ffact(int n){ double r=1.0; for(int i=2;i<=n;++i) r*=i; return r; }

double su2cg(int j1,int m1,int j2,int m2,int j3,int m3){
  if(m3 != m1+m2) return 0.0;
  int vmin = std::max(std::max(-j1+j2+m3, -j1+m1), 0);
  int vmax = std::min(std::min(j2+j3+m1, j3-j1+j2), j3+m3);
  double C = std::sqrt((2.0*j3+1.0)*ffact(j3+j1-j2)*ffact(j3-j1+j2)*ffact(j1+j2-j3)
             /ffact(j1+j2+j3+1)
             *ffact(j3+m3)*ffact(j3-m3)
             /(ffact(j1-m1)*ffact(j1+m1)*ffact(j2-m2)*ffact(j2+m2)));
  double S = 0.0;
  for(int v=vmin; v<=vmax; ++v){
    double t = ffact(j2+j3+m1-v)*ffact(j1-m1+v)
             /(ffact(v)*ffact(j3-j1+j2-v)*ffact(j3+m3-v)*ffact(v+j1-j2-m3));
    S += ((v+j2+m2)&1) ? -t : t;
  }
  return C*S;
}

void cbasis(int l, std::complex<double>* q){
  int n = 2*l+1;
  for(int i=0;i<n*n;++i) q[i] = std::complex<double>(0.0,0.0);
  const double is2 = 1.0/std::sqrt(2.0);
  for(int m=-l; m<0; ++m){
    q[(l+m)*n + (l-m)] = std::complex<double>(is2, 0.0);
    q[(l+m)*n + (l+m)] = std::complex<double>(0.0, -is2);
  }
  q[l*n+l] = std::complex<double>(1.0, 0.0);
  for(int m=1; m<=l; ++m){
    double s = (m&1) ? -1.0 : 1.0;
    q[(l+m)*n + (l+m)] = std::complex<double>(s*is2, 0.0);
    q[(l+m)*n + (l-m)] = std::complex<double>(0.0, s*is2);
  }
  std::complex<double> ph;
  switch(l&3){ case 0: ph = std::complex<double>(1,0);  break;
               case 1: ph = std::complex<double>(0,-1); break;
               case 2: ph = std::complex<double>(-1,0); break;
               default: ph = std::complex<double>(0,1);  break; }
  for(int i=0;i<n*n;++i) q[i] *= ph;
}

void wigner3j_tab(int l1,int l2,int l3, float* dst){
  int n1=2*l1+1, n2=2*l2+1, n3=2*l3+1;
  std::vector<double> C(n1*n2*n3);
  for(int i=0;i<n1;++i) for(int k=0;k<n2;++k) for(int n=0;n<n3;++n)
    C[(i*n2+k)*n3+n] = su2cg(l1,i-l1, l2,k-l2, l3,n-l3);
  std::vector<std::complex<double>> Q1(n1*n1), Q2(n2*n2), Q3(n3*n3);
  cbasis(l1,Q1.data()); cbasis(l2,Q2.data()); cbasis(l3,Q3.data());
  std::vector<double> R(n1*n2*n3, 0.0);
  for(int j=0;j<n1;++j) for(int l=0;l<n2;++l) for(int m=0;m<n3;++m){
    std::complex<double> s(0,0);
    for(int i=0;i<n1;++i) for(int k=0;k<n2;++k) for(int n=0;n<n3;++n)
      s += Q1[i*n1+j]*Q2[k*n2+l]*std::conj(Q3[n*n3+m])*C[(i*n2+k)*n3+n];
    R[(j*n2+l)*n3+m] = s.real();
  }
  double nrm=0; for(double v:R) nrm += v*v; nrm = std::sqrt(nrm);
  for(int t=0;t<n1*n2*n3;++t) dst[t] = (float)(R[t]/nrm);
}

void fill_params(TPParams& P, AlphaArg& A){
  for(int ins=0; ins<15; ++ins)
    wigner3j_tab(I_L1[ins], I_L2[ins], I_LO[ins], P.w3j + W3OFF[ins]);
  int cnt[3] = {0,0,0};
  for(int ins=0; ins<15; ++ins) cnt[I_LO[ins]]++;      // {3,6,6}
  for(int ins=0; ins<15; ++ins){
    int lo = I_LO[ins];
    A.a[ins] = (float)std::sqrt((2.0*lo+1.0)/(128.0*cnt[lo]));
  }
}

} // namespace

// ---------------- device helpers -------------------------------------------
DEVFN unsigned f2bf(float f){                       // fp32 -> bf16 bits (RNE)
  unsigned u = __float_as_uint(f);
  return (u + 0x7fffu + ((u>>16)&1u)) >> 16;
}
DEVFN unsigned pkbf(float a, float b){ return f2bf(a) | (f2bf(b)<<16); }

template<typename T, typename F>
DEVFN T bc(F f){ static_assert(sizeof(T)==sizeof(F), "size"); T t; __builtin_memcpy(&t,&f,sizeof(T)); return t; }

// ---------------- prep: weights -> bf16, alpha folded, swizzled WT ----------
// dst layout (per path p): row w (0..127), 16 groups of 8 consecutive u;
// logical u-group (u>>3) stored at position (u>>3) ^ (w&15)  [bank swizzle]
__global__ __launch_bounds__(256)
void prep_kernel(const float* __restrict__ w, unsigned short* __restrict__ ws,
                 AlphaArg al)
{
  int t = blockIdx.x*256 + threadIdx.x;          // < 15*16384 = 245760
  int p = t >> 14, rem = t & 16383, u = rem >> 7, col = rem & 127;
  float v = w[t] * al.a[p];
  int gs = (u>>3) ^ (col & 15);
  ws[(p<<14) + (col<<7) + (gs<<3) + (u&7)] = (unsigned short)f2bf(v);
}

// ---------------- phase A: xx_p[k][z][u] (bf16, swizzled) -------------------
template<int INS>
DEVFN void path_phaseA(const TPParams& P, const unsigned x1p[9][4],
                       const float x2r[9], uint4* sxxU4, int z, int ug)
{
  constexpr int L1 = I_L1[INS], L2 = I_L2[INS], LO = I_LO[INS];
  constexpr int N1 = 2*L1+1, N2 = 2*L2+1, NO = 2*LO+1;
  constexpr int O1 = LOFF[L1], O2 = LOFF[L2], W3 = W3OFF[INS];

  float cc[NO][N1];
  #pragma unroll
  for(int k=0;k<NO;++k){
    #pragma unroll
    for(int i=0;i<N1;++i){
      float s = 0.f;
      #pragma unroll
      for(int j=0;j<N2;++j)
        s += P.w3j[W3 + (i*N2+j)*NO + k] * x2r[O2 + j];
      cc[k][i] = s;
    }
  }
  float a8[NO][8];
  #pragma unroll
  for(int k=0;k<NO;++k){
    #pragma unroll
    for(int e=0;e<8;++e) a8[k][e]=0.f;
  }
  #pragma unroll
  for(int i=0;i<N1;++i){
    float xf[8];
    #pragma unroll
    for(int pr=0;pr<4;++pr){
      unsigned u = x1p[O1+i][pr];
      xf[2*pr]   = __uint_as_float(u << 16);
      xf[2*pr+1] = __uint_as_float(u & 0xffff0000u);
    }
    #pragma unroll
    for(int k=0;k<NO;++k){
      #pragma unroll
      for(int e=0;e<8;++e) a8[k][e] += cc[k][i]*xf[e];
    }
  }
  #pragma unroll
  for(int k=0;k<NO;++k){
    uint4 o;
    o.x = pkbf(a8[k][0], a8[k][1]);
    o.y = pkbf(a8[k][2], a8[k][3]);
    o.z = pkbf(a8[k][4], a8[k][5]);
    o.w = pkbf(a8[k][6], a8[k][7]);
    sxxU4[(k*16 + z)*16 + ((ug ^ z) & 15)] = o;
  }
}

// ---------------- GEMM phase: acc[t][ct] += xx_p . WT_p ---------------------
template<int INS>
DEVFN void path_gemm(const uint4* sxxU4, const uint4* sWTU4,
                     f32x4 acc[9][2], int lane, int wv)
{
  constexpr int LO = I_LO[INS], NO = 2*LO+1, OO = LOFF[LO];
  const int m = lane & 15, q = lane >> 4;
  #pragma unroll
  for(int ks=0; ks<4; ++ks){
    const int g  = ks*4 + q;
    const int gp = (g ^ m) & 15;          // swizzled group position
    short8 a[NO];
    #pragma unroll
    for(int k=0;k<NO;++k)
      a[k] = bc<short8>(sxxU4[(k*16 + m)*16 + gp]);
    #pragma unroll
    for(int ct=0; ct<2; ++ct){
      const int w = (wv*2 + ct)*16 + m;   // (w & 15) == m
      short8 b = bc<short8>(sWTU4[w*16 + gp]);
      #pragma unroll
      for(int k=0;k<NO;++k)
        acc[OO+k][ct] = __builtin_amdgcn_mfma_f32_16x16x32_bf16(a[k], b, acc[OO+k][ct], 0,0,0);
    }
  }
}

DEVFN void stage_wt(const uint4* __restrict__ wsrc, uint4* sWT, int tid){
  #pragma unroll
  for(int r=0;r<8;++r){
    uint4 v = wsrc[r*256 + tid];
    sWT[r*256 + tid] = v;
  }
}

// ---------------- main kernel -----------------------------------------------
__global__ __launch_bounds__(256, 2)
void tp_kernel(const float* __restrict__ x1, const float* __restrict__ x2,
               const unsigned short* __restrict__ wsb, float* __restrict__ out,
               TPParams P)
{
  __shared__ uint4 sxxU4[5*16*16];   // 20480 B  xx_p, bf16 swizzled
  __shared__ uint4 sWTU4[2048];      // 32768 B  WT_p, bf16 swizzled

  const int tid = threadIdx.x;
  const long zbase = (long)blockIdx.x * TILE_Z;
  const int z = tid >> 4, ug = tid & 15;       // phase-A mapping
  const int lane = tid & 63, wv = tid >> 6;    // GEMM mapping

  // x1 slice -> 36 packed-bf16 VGPRs; x2 -> 9 fp32 VGPRs
  unsigned x1p[9][4];
  float x2r[9];
  {
    const float* xsrc = x1 + (zbase + z)*1152 + ug*8;
    #pragma unroll
    for(int i=0;i<9;++i){
      float4 a = *reinterpret_cast<const float4*>(xsrc + i*128);
      float4 b = *reinterpret_cast<const float4*>(xsrc + i*128 + 4);
      x1p[i][0] = pkbf(a.x, a.y); x1p[i][1] = pkbf(a.z, a.w);
      x1p[i][2] = pkbf(b.x, b.y); x1p[i][3] = pkbf(b.z, b.w);
    }
    #pragma unroll
    for(int j=0;j<9;++j) x2r[j] = x2[(zbase + z)*9 + j];
  }

  f32x4 acc[9][2];
  #pragma unroll
  for(int t=0;t<9;++t){
    #pragma unroll
    for(int c=0;c<2;++c){ f32x4 zz = {0.f,0.f,0.f,0.f}; acc[t][c] = zz; }
  }

  const uint4* wsbU4 = reinterpret_cast<const uint4*>(wsb);

#define DO_PATH(n)                                               \
  stage_wt(wsbU4 + (n)*2048, sWTU4, tid);                        \
  path_phaseA<n>(P, x1p, x2r, sxxU4, z, ug);                     \
  __syncthreads();                                               \
  path_gemm<n>(sxxU4, sWTU4, acc, lane, wv);                     \
  __syncthreads();

  DO_PATH(0)  DO_PATH(1)  DO_PATH(2)  DO_PATH(3)  DO_PATH(4)
  DO_PATH(5)  DO_PATH(6)  DO_PATH(7)  DO_PATH(8)  DO_PATH(9)
  DO_PATH(10) DO_PATH(11) DO_PATH(12) DO_PATH(13) DO_PATH(14)
#undef DO_PATH

  // epilogue: D layout col=lane&15, row=(lane>>4)*4+reg
  const int col = lane & 15, q = lane >> 4;
  #pragma unroll
  for(int t=0;t<9;++t){
    #pragma unroll
    for(int ct=0;ct<2;++ct){
      #pragma unroll
      for(int r=0;r<4;++r)
        out[(zbase + q*4 + r)*1152 + t*128 + (wv*2 + ct)*16 + col] = acc[t][ct][r];
    }
  }
}

extern "C" void kernel_launch(void* const* d_in, const int* in_sizes, int n_in,
                              void* d_out, int out_size, void* d_ws, size_t ws_size,
                              hipStream_t stream)
{
  (void)in_sizes; (void)n_in; (void)out_size; (void)ws_size;
  const float* x1 = (const float*)d_in[0];
  const float* x2 = (const float*)d_in[1];
  const float* wt = (const float*)d_in[2];
  float* out = (float*)d_out;
  unsigned short* wsb = (unsigned short*)d_ws;   // 491,520 B used

  TPParams P; AlphaArg A;
  fill_params(P, A);

  prep_kernel<<<dim3(960), dim3(256), 0, stream>>>(wt, wsb, A);
  tp_kernel<<<dim3(NBLOCK), dim3(256), 0, stream>>>(x1, x2, wsb, out, P);
}